// Round 15
// baseline (899.007 us; speedup 1.0000x reference)
//
#include <hip/hip_runtime.h>
#include <hip/hip_bf16.h>

// HisRepItself round 15: split each batch across 2 blocks (f-halves) to use
// all 256 CUs. Per layer: compute own f-half -> publish to global yx (parity
// double buffer) -> release flag -> acquire-spin on partner -> reload full y
// to LDS. Pairs (b, b^128) share an XCD under round-robin; correctness uses
// device-scope atomics/fences regardless (G16). Flags memset per launch.
// LDS 78.7KB/block -> 2 blocks/CU capacity -> all 256 blocks co-resident.
//
// Workspace (f32 units), ~25.8 MB:
//   dct 0 | x 512 | x_bf 169472 | wgT 333312 | gc1wT 1119744 | w1T 1123840
//   w2T 1254912 | kc1q 1582592 | key 2237952 | q 3253760 | bnP 3290624
//   aG 3713024 | w7T 3812864 | flags 3816960 (6400 ints) | yx 3823360

typedef __attribute__((ext_vector_type(8))) short short8;
typedef __attribute__((ext_vector_type(4))) float float4v;
typedef __attribute__((ext_vector_type(4))) unsigned uint4v;

#define BNI 0.9999950000374995f

__device__ __forceinline__ short f2bf(float x){
  unsigned u = __float_as_uint(x);
  unsigned r = (u + 0x7fff + ((u >> 16) & 1)) >> 16;
  return (short)r;
}
__device__ __forceinline__ unsigned pk2(float a, float b){
  unsigned r;
  asm("v_cvt_pk_bf16_f32 %0, %1, %2" : "=v"(r) : "v"(a), "v"(b));
  return r;
}
__device__ __forceinline__ float tanh_f(float x){
  x = fminf(fmaxf(x, -9.f), 9.f);
  float e = __expf(2.f * x);
  return (e - 1.f) * __builtin_amdgcn_rcpf(e + 1.f);
}

// ---------------- merged prep kernel ----------------
// grid: [0,2) dct | [2,1026) wconv1 | [1026,3586) wconv2 | [3586,3970) wgcn
//  [3970,4002) wgc1 | [4002,4782) aG | [4782,6432) bnpack | [6432,6464) w7T
__global__ __launch_bounds__(256) void k_prep(
    const float* __restrict__ wK1, const float* __restrict__ wQ1,
    const float* __restrict__ wK2, const float* __restrict__ wQ2,
    const float* __restrict__ gw1, const float* __restrict__ gw2,
    const float* __restrict__ gc1_w, const float* __restrict__ gc7_w,
    const float* __restrict__ gc1_att, const float* __restrict__ att1,
    const float* __restrict__ att2, const float* __restrict__ gc7_att,
    const float* __restrict__ g0, const float* __restrict__ be0, const float* __restrict__ b0,
    const float* __restrict__ g1a, const float* __restrict__ be1a, const float* __restrict__ b1a,
    const float* __restrict__ g2a, const float* __restrict__ be2a, const float* __restrict__ b2a,
    float* __restrict__ dct, short* __restrict__ w1T, short* __restrict__ w2T,
    short* __restrict__ wgT, short* __restrict__ gc1wT, short* __restrict__ aG,
    unsigned* __restrict__ bnP, short* __restrict__ w7T)
{
  __shared__ short tle[64][72];
  int bid = blockIdx.x, tid = threadIdx.x;
  if (bid < 2){
    int t = bid*256 + tid;
    if (t < 400){
      int k = t / 20, i = t % 20;
      double w = (k == 0) ? sqrt(1.0/20.0) : sqrt(2.0/20.0);
      dct[t] = (float)(w * cos(3.14159265358979323846 * (i + 0.5) * k / 20.0));
    }
  } else if (bid < 1026){
    int idx = (bid-2)*256 + tid;
    int f = idx >> 9, k = idx & 511;
    float v = 0.f;
    if (k < 396){
      int h = k / 66, c = k - h*66;
      const float* s = (f < 256) ? wK1 : wQ1;
      v = s[((f & 255)*66 + c)*6 + h];
    }
    w1T[idx] = f2bf(v);
  } else if (bid < 3586){
    int idx = (bid-1026)*256 + tid;
    int f = idx / 1280, k = idx - f*1280;
    int h = k >> 8, c = k & 255;
    const float* s = (f < 256) ? wK2 : wQ2;
    w2T[idx] = f2bf(s[((f & 255)*256 + c)*5 + h]);
  } else if (bid < 3970){
    int q = bid - 3586;
    int l = q >> 4, sub = q & 15;
    int kt = (sub >> 2)*64, ft = (sub & 3)*64;
    const float* s = (l < 12) ? (gw1 + l*65536) : (gw2 + (l-12)*65536);
    int c = tid & 63, r4 = tid >> 6;
    #pragma unroll
    for (int p = 0; p < 16; p++){
      int k = p*4 + r4;
      tle[k][c] = f2bf(s[(kt + k)*256 + ft + c]);
    }
    __syncthreads();
    #pragma unroll
    for (int p = 0; p < 16; p++){
      int f = p*4 + r4;
      wgT[l*65536 + (ft + f)*256 + kt + c] = tle[c][f];
    }
  } else if (bid < 4002){
    int idx = (bid-3970)*256 + tid;
    int f = idx >> 5, k = idx & 31;
    gc1wT[idx] = f2bf(k < 20 ? gc1_w[k*256 + f] : 0.f);
  } else if (bid < 4782){
    int idx = (bid-4002)*256 + tid;   // < 26*7680
    int li = idx / 7680, r = idx - li*7680;
    int n = r / 96, m = r - n*96;
    const float* Af;
    if (li == 0) Af = gc1_att;
    else if (li == 25) Af = gc7_att;
    else if (li & 1) Af = att1 + ((li-1)>>1)*4356;
    else             Af = att2 + ((li-2)>>1)*4356;
    aG[idx] = f2bf((n < 66 && m < 66) ? Af[n*66 + m] : 0.f);
  } else if (bid < 6432){
    int idx = (bid-4782)*256 + tid;
    if (idx < 25*16896){
      int li = idx / 16896, r = idx - li*16896;
      int f = r & 255;
      const float *g, *be, *bi;
      if (li == 0){ g = g0; be = be0; bi = b0; }
      else {
        int l = (li - 1) >> 1;
        if (li & 1){ g = g1a + l*16896; be = be1a + l*16896; bi = b1a + l*256; }
        else       { g = g2a + l*16896; be = be2a + l*16896; bi = b2a + l*256; }
      }
      float sc = g[r] * BNI;
      float sh = bi[f] * sc + be[r];
      bnP[idx] = pk2(sc, sh);
    }
  } else {
    int idx = (bid-6432)*256 + tid;   // < 8192
    int f = idx >> 8, k = idx & 255;
    w7T[idx] = f2bf(f < 20 ? gc7_w[k*20 + f] : 0.f);
  }
}

// ---------------- conv1 (proven) ----------------
__global__ __launch_bounds__(256) void k_conv1(const float* __restrict__ src,
    const short* __restrict__ w1T, short* __restrict__ kc1q){
  int b = blockIdx.x, ns = blockIdx.y;
  int f0 = ns*128;
  __shared__ short Aim[48*424];
  __shared__ short Wt[128*72];
  int tid = threadIdx.x;
  for (int idx = tid; idx < 48*424; idx += 256){
    int t = idx / 424, kk = idx - t*424;
    float v = 0.f;
    if (kk < 396 && t < 40){
      int h = kk / 66, c = kk - h*66;
      int row = t + h + ((t >= 35) ? 5 : 0);
      v = src[(b*50 + row)*66 + c] * 1e-3f;
    }
    Aim[idx] = f2bf(v);
  }
  int w = tid >> 6, lane = tid & 63, fl = lane & 15, g = lane >> 4;
  float4v acc[3][2];
  #pragma unroll
  for (int i=0;i<3;i++) for (int n=0;n<2;n++) acc[i][n] = (float4v){0.f,0.f,0.f,0.f};
  for (int kt = 0; kt < 416; kt += 64){
    __syncthreads();
    for (int ch = tid; ch < 128*8; ch += 256){
      int r = ch >> 3, kq = ch & 7;
      *(short8*)&Wt[r*72 + kq*8] = *(const short8*)&w1T[(f0 + r)*512 + kt + kq*8];
    }
    __syncthreads();
    int nst = (416 - kt >= 64) ? 2 : 1;
    for (int s = 0; s < nst; s++){
      int k0 = s*32;
      short8 bfr0 = *(const short8*)&Wt[(w*32 + fl)*72 + k0 + g*8];
      short8 bfr1 = *(const short8*)&Wt[(w*32 + 16 + fl)*72 + k0 + g*8];
      #pragma unroll
      for (int i=0;i<3;i++){
        short8 afr = *(const short8*)&Aim[(i*16 + fl)*424 + kt + k0 + g*8];
        acc[i][0] = __builtin_amdgcn_mfma_f32_16x16x32_bf16(afr, bfr0, acc[i][0], 0,0,0);
        acc[i][1] = __builtin_amdgcn_mfma_f32_16x16x32_bf16(afr, bfr1, acc[i][1], 0,0,0);
      }
    }
  }
  #pragma unroll
  for (int i=0;i<3;i++) for (int n=0;n<2;n++) for (int j=0;j<4;j++){
    int t = i*16 + g*4 + j;
    int f = f0 + w*32 + n*16 + fl;
    float v = fmaxf(acc[i][n][j], 0.f);
    if (t < 35 && f < 256) kc1q[(b*40 + t)*256 + f] = f2bf(v);
    else if (t >= 35 && t < 40 && f >= 256) kc1q[(b*40 + t)*256 + (f - 256)] = f2bf(v);
  }
}

// ---------------- conv2 (proven) ----------------
__global__ __launch_bounds__(256) void k_conv2(const short* __restrict__ kc1q,
    const short* __restrict__ w2T, float* __restrict__ key, float* __restrict__ q){
  int b = blockIdx.x, ns = blockIdx.y;
  int f0 = ns*128;
  __shared__ short kcs[40*256];
  __shared__ short Wt[128*136];
  char* kcb = (char*)kcs;
  int tid = threadIdx.x;
  for (int ch = tid; ch < 1280; ch += 256){
    int r = ch >> 5, kq = ch & 31;
    unsigned byte = (unsigned)(r*512 + kq*16) ^ (unsigned)((r & 7) << 4);
    *(short8*)(kcb + byte) = *(const short8*)&kc1q[(b*40 + r)*256 + kq*8];
  }
  int w = tid >> 6, lane = tid & 63, fl = lane & 15, g = lane >> 4;
  float4v acc[2][2];
  #pragma unroll
  for (int i=0;i<2;i++) for (int n=0;n<2;n++) acc[i][n] = (float4v){0.f,0.f,0.f,0.f};
  for (int kt = 0; kt < 1280; kt += 128){
    __syncthreads();
    for (int ch = tid; ch < 128*16; ch += 256){
      int r = ch >> 4, kq = ch & 15;
      *(short8*)&Wt[r*136 + kq*8] = *(const short8*)&w2T[(f0 + r)*1280 + kt + kq*8];
    }
    __syncthreads();
    #pragma unroll
    for (int s = 0; s < 4; s++){
      int k = kt + s*32;
      int h = k >> 8, cb = k & 255;
      short8 bfr0 = *(const short8*)&Wt[(w*32 + fl)*136 + s*32 + g*8];
      short8 bfr1 = *(const short8*)&Wt[(w*32 + 16 + fl)*136 + s*32 + g*8];
      #pragma unroll
      for (int i=0;i<2;i++){
        int t = i*16 + fl;
        int row = t + h + ((t == 31) ? 4 : 0);
        unsigned byte = (unsigned)(row*512 + (cb + g*8)*2) ^ (unsigned)((row & 7) << 4);
        short8 afr = *(const short8*)(kcb + byte);
        acc[i][0] = __builtin_amdgcn_mfma_f32_16x16x32_bf16(afr, bfr0, acc[i][0], 0,0,0);
        acc[i][1] = __builtin_amdgcn_mfma_f32_16x16x32_bf16(afr, bfr1, acc[i][1], 0,0,0);
      }
    }
  }
  #pragma unroll
  for (int i=0;i<2;i++) for (int n=0;n<2;n++) for (int j=0;j<4;j++){
    int t = i*16 + g*4 + j;
    int f = f0 + w*32 + n*16 + fl;
    float v = fmaxf(acc[i][n][j], 0.f);
    if (t < 31 && f < 256) key[(b*31 + t)*256 + f] = v;
    else if (t == 31 && f >= 256) q[b*256 + f - 256] = v;
  }
}

// ---------------- fused attention + build_x (proven) ----------------
__global__ __launch_bounds__(256) void k_attx(const float* __restrict__ src,
    const float* __restrict__ q, const float* __restrict__ key,
    const float* __restrict__ dct, float* __restrict__ x, short* __restrict__ x_bf){
  int b = blockIdx.x;
  int tid = threadIdx.x;
  __shared__ float sred[31][9];
  __shared__ float a[31];
  __shared__ float z[20*66];
  for (int i = tid; i < 2560; i += 256) x_bf[b*2560 + i] = 0;
  if (tid < 248){
    int v = tid >> 3, p = tid & 7;
    const float* kr = key + (b*31 + v)*256 + p*32;
    const float* qr = q + b*256 + p*32;
    float s = 0.f;
    #pragma unroll
    for (int o = 0; o < 32; o++) s += qr[o] * kr[o];
    sred[v][p] = s;
  }
  __syncthreads();
  if (tid < 31){
    float s = 1e-15f;
    #pragma unroll
    for (int p = 0; p < 8; p++) s += sred[tid][p];
    sred[tid][8] = s;
  }
  __syncthreads();
  if (tid < 64){
    float v = (tid < 31) ? sred[tid][8] : 0.f;
    float tot = v;
    for (int off = 32; off; off >>= 1) tot += __shfl_down(tot, off);
    tot = __shfl(tot, 0);
    if (tid < 31) a[tid] = v / tot;
  }
  __syncthreads();
  for (int idx = tid; idx < 1320; idx += 256){
    int i = idx / 66, f = idx % 66;
    float s = 0.f;
    for (int v = 0; v < 31; v++) s += a[v] * src[(b*50 + v + i)*66 + f];
    z[idx] = s;
  }
  __syncthreads();
  for (int idx = tid; idx < 660; idx += 256){
    int f = idx / 10, k = idx % 10;
    float s1 = 0.f, s2 = 0.f;
    #pragma unroll
    for (int i = 0; i < 20; i++){
      float d = dct[k*20 + i];
      int tt = (i < 10) ? (40 + i) : 49;
      s1 += d * src[(b*50 + tt)*66 + f];
      s2 += d * z[i*66 + f];
    }
    x[(b*66 + f)*20 + k] = s1;
    x[(b*66 + f)*20 + 10 + k] = s2;
    x_bf[(b*80 + f)*32 + k] = f2bf(s1);
    x_bf[(b*80 + f)*32 + 10 + k] = f2bf(s2);
  }
}

// ---------------- mega2: 2 blocks per batch (f-halves) ----------------
// LDS (byte ^= ((row&15)<<4)):
//   ybf [80 m][512 B] (full y) | tT [128 fw][256 B] (wave-local rows)
// Block bb: b = bb&127 (batch), h = bb>>7 (f-half). Wave w owns fw [16w,16w+16).

// MODE: 0 = y_r = v (gc1), 1 = h-layer, 2 = y_r += v
template<int KSTEPS, int KSTRIDE, int MODE>
__device__ __forceinline__ void layer2(
    const short* __restrict__ Wg,
    const unsigned* __restrict__ bnl, const short* __restrict__ aGl,
    int lay, int b, int h, int fb,
    float4v (&y_r)[5], int tid, int w, int fl, int g,
    char* __restrict__ ybf_c, char* __restrict__ tT_c,
    short* __restrict__ yx, int* __restrict__ flags)
{
  const short* wbase = Wg + (fb + w*16 + fl)*KSTRIDE + g*8;
  short8 bw[4];
  bw[0] = *(const short8*)(wbase);
  if (KSTEPS > 1) bw[1] = *(const short8*)(wbase + 32);
  if (KSTEPS > 2) bw[2] = *(const short8*)(wbase + 64);

  // ---- G1: t[:, my 16 f] = y @ W ----
  float4v acc[5];
  #pragma unroll
  for (int i=0;i<5;i++) acc[i] = (float4v){0.f,0.f,0.f,0.f};
  __builtin_amdgcn_s_setprio(1);
  #pragma unroll
  for (int ks=0; ks<KSTEPS; ks++){
    if (ks + 3 < KSTEPS) bw[(ks+3)&3] = *(const short8*)(wbase + (ks+3)*32);
    #pragma unroll
    for (int i=0;i<5;i++){
      int m = i*16 + fl;
      short8 af = *(const short8*)(ybf_c + m*512 + ((ks*64 + g*16) ^ ((m & 15) << 4)));
      acc[i] = __builtin_amdgcn_mfma_f32_16x16x32_bf16(af, bw[ks&3], acc[i], 0,0,0);
    }
  }
  __builtin_amdgcn_s_setprio(0);

  short8 bA[5];
  #pragma unroll
  for (int n2=0;n2<5;n2++)
    bA[n2] = *(const short8*)&aGl[(n2*16 + fl)*96 + g*8];

  int fw = w*16 + fl;
  #pragma unroll
  for (int i=0;i<5;i++){
    int mb = (i*16 + g*4)*2;
    uint2 u; u.x = pk2(acc[i][0], acc[i][1]); u.y = pk2(acc[i][2], acc[i][3]);
    *(uint2*)(tT_c + fw*256 + (mb ^ ((fw & 15) << 4))) = u;
  }
  uint4v bnp[5];
  #pragma unroll
  for (int n2=0;n2<5;n2++){
    int n = n2*16 + fl; int ns = (n < 66) ? n : 0;
    bnp[n2] = *(const uint4v*)&bnl[ns*256 + fb + w*16 + g*4];
  }

  // ---- G2: o = A @ t (tT rows wave-local) ----
  float4v a2[5];
  #pragma unroll
  for (int n2=0;n2<5;n2++) a2[n2] = (float4v){0.f,0.f,0.f,0.f};
  #pragma unroll
  for (int ks2=0; ks2<3; ks2++){
    __builtin_amdgcn_s_setprio(1);
    short8 af = *(const short8*)(tT_c + fw*256 + ((ks2*64 + g*16) ^ ((fw & 15) << 4)));
    #pragma unroll
    for (int n2=0;n2<5;n2++)
      a2[n2] = __builtin_amdgcn_mfma_f32_16x16x32_bf16(af, bA[n2], a2[n2], 0,0,0);
    __builtin_amdgcn_s_setprio(0);
    if (ks2 < 2){
      #pragma unroll
      for (int n2=0;n2<5;n2++)
        bA[n2] = *(const short8*)&aGl[(n2*16 + fl)*96 + (ks2+1)*32 + g*8];
    }
  }

  // ---- epilogue: BN + tanh [+res] -> global yx (own half) ----
  short* yxp = yx + ((size_t)(lay & 1) * 128 + b) * 20480;
  #pragma unroll
  for (int n2=0;n2<5;n2++){
    int n = n2*16 + fl;
    bool nok = (n < 66);
    float vv[4];
    #pragma unroll
    for (int j=0;j<4;j++){
      unsigned u = bnp[n2][j];
      float sc = __uint_as_float((u & 0xffffu) << 16);
      float sh = __uint_as_float(u & 0xffff0000u);
      float v = a2[n2][j]*sc + sh;
      v = tanh_f(v);
      if (MODE == 0) y_r[n2][j] = v;
      if (MODE == 2){ v += y_r[n2][j]; y_r[n2][j] = v; }
      vv[j] = nok ? v : 0.f;
    }
    uint2 u2; u2.x = pk2(vv[0], vv[1]); u2.y = pk2(vv[2], vv[3]);
    *(uint2*)(yxp + n*256 + fb + w*16 + g*4) = u2;
  }

  // ---- exchange: signal own half, wait partner, reload full y ----
  __syncthreads();                 // all reads of old ybf done; stores drained
  if (tid == 0){
    __threadfence();
    __hip_atomic_store(&flags[lay*256 + b*2 + h], 1,
                       __ATOMIC_RELEASE, __HIP_MEMORY_SCOPE_AGENT);
    int c = 0;
    while (__hip_atomic_load(&flags[lay*256 + b*2 + (1 - h)],
                             __ATOMIC_ACQUIRE, __HIP_MEMORY_SCOPE_AGENT) == 0){
      if (++c > (1 << 23)) break;  // bounded spin: never hang
    }
  }
  __syncthreads();
  __builtin_amdgcn_fence(__ATOMIC_ACQUIRE, "agent");
  for (int i = tid; i < 2560; i += 512){
    int m = i >> 5, kq = i & 31;
    short8 v = *(const short8*)(yxp + m*256 + kq*8);
    *(short8*)(ybf_c + m*512 + ((kq*16) ^ ((m & 15) << 4))) = v;
  }
  __syncthreads();
}

__global__ __launch_bounds__(512) void k_mega2(const short* __restrict__ x_bf,
    const short* __restrict__ gc1wT, const short* __restrict__ wgT,
    const short* __restrict__ aG, const unsigned* __restrict__ bnP,
    const short* __restrict__ w7T, const float* __restrict__ gc7_b,
    const float* __restrict__ x, const float* __restrict__ dct,
    short* __restrict__ yx, int* __restrict__ flags,
    float* __restrict__ out)
{
  __shared__ __align__(16) char ybf_c[40960];
  __shared__ __align__(16) char tT_c[32768];
  __shared__ float xo_l[1320];
  __shared__ float dct_l[400];

  int bb = blockIdx.x, tid = threadIdx.x;
  int b = bb & 127, h = bb >> 7, fb = h*128;
  int w = tid >> 6, lane = tid & 63, fl = lane & 15, g = lane >> 4;

  for (int i = tid; i < 2048; i += 512) ((float4v*)tT_c)[i] = (float4v){0.f,0.f,0.f,0.f};
  for (int i = tid; i < 400; i += 512) dct_l[i] = dct[i];
  for (int i = tid; i < 320; i += 512){
    int m = i >> 2, kq = i & 3;
    short8 v = *(const short8*)&x_bf[(b*80 + m)*32 + kq*8];
    *(short8*)(ybf_c + m*512 + ((kq*16) ^ ((m & 15) << 4))) = v;
  }
  __syncthreads();

  float4v y_r[5];

  layer2<1,32,0>(gc1wT, bnP, aG, 0, b, h, fb, y_r, tid, w, fl, g,
                 ybf_c, tT_c, yx, flags);
  #pragma unroll 1
  for (int l = 0; l < 12; l++){
    layer2<8,256,1>(wgT + l*65536, bnP + (1+2*l)*16896, aG + (1+2*l)*7680,
                    1+2*l, b, h, fb, y_r, tid, w, fl, g, ybf_c, tT_c, yx, flags);
    layer2<8,256,2>(wgT + (12+l)*65536, bnP + (2+2*l)*16896, aG + (2+2*l)*7680,
                    2+2*l, b, h, fb, y_r, tid, w, fl, g, ybf_c, tT_c, yx, flags);
  }
  // ybf now holds final y (both halves). Tail computed by both blocks
  // (identical values; duplicate identical stores are benign).

  // G1t: t2 = y @ w7 (N=32, K=256) -- w7 frags straight from global w7T
  float4v at[5][2];
  #pragma unroll
  for (int i=0;i<5;i++){ at[i][0] = (float4v){0.f,0.f,0.f,0.f}; at[i][1] = (float4v){0.f,0.f,0.f,0.f}; }
  #pragma unroll
  for (int ks = 0; ks < 8; ks++){
    short8 bf[2];
    #pragma unroll
    for (int n=0;n<2;n++)
      bf[n] = *(const short8*)&w7T[(n*16 + fl)*256 + ks*32 + g*8];
    #pragma unroll
    for (int i=0;i<5;i++){
      int m = i*16 + fl;
      short8 af = *(const short8*)(ybf_c + m*512 + ((ks*64 + g*16) ^ ((m & 15) << 4)));
      at[i][0] = __builtin_amdgcn_mfma_f32_16x16x32_bf16(af, bf[0], at[i][0], 0,0,0);
      at[i][1] = __builtin_amdgcn_mfma_f32_16x16x32_bf16(af, bf[1], at[i][1], 0,0,0);
    }
  }
  if (w == 0){
    #pragma unroll
    for (int i=0;i<5;i++){
      int mb = (i*16 + g*4)*2;
      #pragma unroll
      for (int n=0;n<2;n++){
        int f = n*16 + fl;
        uint2 u; u.x = pk2(at[i][n][0], at[i][n][1]); u.y = pk2(at[i][n][2], at[i][n][3]);
        *(uint2*)(tT_c + f*256 + (mb ^ ((f & 15) << 4))) = u;
      }
    }
  }
  short8 bAt[15];
  {
    const short* aGt = aG + 25*7680;
    #pragma unroll
    for (int ks=0;ks<3;ks++)
      #pragma unroll
      for (int n2=0;n2<5;n2++)
        bAt[ks*5+n2] = *(const short8*)&aGt[(n2*16 + fl)*96 + ks*32 + g*8];
  }
  __syncthreads();

  // G2't: out'[f][n] = t2_T @ A7^T, w0 epilogue
  float4v a2t[2][5];
  #pragma unroll
  for (int i=0;i<2;i++)
    #pragma unroll
    for (int n=0;n<5;n++) a2t[i][n] = (float4v){0.f,0.f,0.f,0.f};
  #pragma unroll
  for (int ks = 0; ks < 3; ks++){
    #pragma unroll
    for (int i2=0;i2<2;i2++){
      int f = i2*16 + fl;
      short8 af = *(const short8*)(tT_c + f*256 + ((ks*64 + g*16) ^ ((f & 15) << 4)));
      #pragma unroll
      for (int n2=0;n2<5;n2++)
        a2t[i2][n2] = __builtin_amdgcn_mfma_f32_16x16x32_bf16(af, bAt[ks*5+n2], a2t[i2][n2], 0,0,0);
    }
  }
  if (w == 0){
    #pragma unroll
    for (int i2=0;i2<2;i2++){
      #pragma unroll
      for (int n2=0;n2<5;n2++){
        int n = n2*16 + fl;
        #pragma unroll
        for (int j=0;j<4;j++){
          int f = i2*16 + g*4 + j;
          if (f < 20 && n < 66)
            xo_l[n*20 + f] = a2t[i2][n2][j] + gc7_b[f] + x[(b*66 + n)*20 + f];
        }
      }
    }
  }
  __syncthreads();

  for (int idx = tid; idx < 1320; idx += 512){
    int r = idx / 66, fn = idx % 66;
    float s = 0.f;
    #pragma unroll
    for (int k = 0; k < 10; k++) s += dct_l[k*20 + r] * xo_l[fn*20 + k];
    out[(b*20 + r)*66 + fn] = s;
  }
}

extern "C" void kernel_launch(void* const* d_in, const int* in_sizes, int n_in,
                              void* d_out, int out_size, void* d_ws, size_t ws_size,
                              hipStream_t stream) {
  const float* src      = (const float*)d_in[0];
  const float* convQ_w1 = (const float*)d_in[1];
  const float* convQ_w2 = (const float*)d_in[2];
  const float* convK_w1 = (const float*)d_in[3];
  const float* convK_w2 = (const float*)d_in[4];
  const float* gc1_w    = (const float*)d_in[5];
  const float* gc1_att  = (const float*)d_in[6];
  const float* gc1_b    = (const float*)d_in[7];
  const float* bn1_g    = (const float*)d_in[8];
  const float* bn1_b    = (const float*)d_in[9];
  const float* gcb_w1   = (const float*)d_in[10];
  const float* gcb_att1 = (const float*)d_in[11];
  const float* gcb_b1   = (const float*)d_in[12];
  const float* gcb_bn1g = (const float*)d_in[13];
  const float* gcb_bn1b = (const float*)d_in[14];
  const float* gcb_w2   = (const float*)d_in[15];
  const float* gcb_att2 = (const float*)d_in[16];
  const float* gcb_b2   = (const float*)d_in[17];
  const float* gcb_bn2g = (const float*)d_in[18];
  const float* gcb_bn2b = (const float*)d_in[19];
  const float* gc7_w    = (const float*)d_in[20];
  const float* gc7_att  = (const float*)d_in[21];
  const float* gc7_b    = (const float*)d_in[22];
  float* out = (float*)d_out;

  float* ws    = (float*)d_ws;
  float* dct   = ws;
  float* x     = ws + 512;
  short* x_bf  = (short*)(ws + 169472);
  short* wgT   = (short*)(ws + 333312);
  short* gc1wT = (short*)(ws + 1119744);
  short* w1T   = (short*)(ws + 1123840);
  short* w2T   = (short*)(ws + 1254912);
  short* kc1q  = (short*)(ws + 1582592);
  float* key   = ws + 2237952;
  float* q     = ws + 3253760;
  unsigned* bnP= (unsigned*)(ws + 3290624);
  short* aG    = (short*)(ws + 3713024);
  short* w7T   = (short*)(ws + 3812864);
  int*   flags = (int*)(ws + 3816960);
  short* yx    = (short*)(ws + 3823360);

  k_prep<<<6464, 256, 0, stream>>>(convK_w1, convQ_w1, convK_w2, convQ_w2,
      gcb_w1, gcb_w2, gc1_w, gc7_w,
      gc1_att, gcb_att1, gcb_att2, gc7_att,
      bn1_g, bn1_b, gc1_b, gcb_bn1g, gcb_bn1b, gcb_b1,
      gcb_bn2g, gcb_bn2b, gcb_b2,
      dct, w1T, w2T, wgT, gc1wT, aG, bnP, w7T);

  hipMemsetAsync(flags, 0, 6400*sizeof(int), stream);

  k_conv1<<<dim3(128,4), 256, 0, stream>>>(src, w1T, kc1q);
  k_conv2<<<dim3(128,4), 256, 0, stream>>>(kc1q, w2T, key, q);
  k_attx<<<128, 256, 0, stream>>>(src, q, key, dct, x, x_bf);

  k_mega2<<<256, 512, 0, stream>>>(x_bf, gc1wT, wgT, aG, bnP,
      w7T, gc7_b, x, dct, yx, flags, out);
}

// Round 16
// 288.527 us; speedup vs baseline: 3.1159x; 3.1159x over previous
//
#include <hip/hip_runtime.h>
#include <hip/hip_bf16.h>

// HisRepItself round 16: revert to r13 (best: 288.9us total, mega 218us).
//  r15's cross-block exchange cost ~20us/layer (mega2 834us) -- split-batch
//  decomposition is dead. r13 = single-barrier mega, wave-local tT, ybf
//  double buffer, per-ks A reload from global aG, cvt_pk packing, setprio.
//
// Workspace (f32 units), total 3,812,864 floats = 15.3 MB:
//   dct 0 | x 512 | x_bf 169472 | wgT 333312 | gc1wT 1119744 | w1T 1123840
//   w2T 1254912 | kc1q 1582592 | key 2237952 | q 3253760 | bnP 3290624
//   aG 3713024 (26*7680 shorts)

typedef __attribute__((ext_vector_type(8))) short short8;
typedef __attribute__((ext_vector_type(4))) float float4v;
typedef __attribute__((ext_vector_type(4))) unsigned uint4v;

#define BNI 0.9999950000374995f

__device__ __forceinline__ short f2bf(float x){
  unsigned u = __float_as_uint(x);
  unsigned r = (u + 0x7fff + ((u >> 16) & 1)) >> 16;
  return (short)r;
}
__device__ __forceinline__ unsigned pk2(float a, float b){
  unsigned r;
  asm("v_cvt_pk_bf16_f32 %0, %1, %2" : "=v"(r) : "v"(a), "v"(b));
  return r;
}
__device__ __forceinline__ float tanh_f(float x){
  x = fminf(fmaxf(x, -9.f), 9.f);
  float e = __expf(2.f * x);
  return (e - 1.f) * __builtin_amdgcn_rcpf(e + 1.f);
}

// ---------------- merged prep kernel (proven) ----------------
// grid: [0,2) dct | [2,1026) wconv1 | [1026,3586) wconv2 | [3586,3970) wgcn
//       [3970,4002) wgc1 | [4002,4782) aG | [4782,6432) bnpack
__global__ __launch_bounds__(256) void k_prep(
    const float* __restrict__ wK1, const float* __restrict__ wQ1,
    const float* __restrict__ wK2, const float* __restrict__ wQ2,
    const float* __restrict__ gw1, const float* __restrict__ gw2,
    const float* __restrict__ gc1_w,
    const float* __restrict__ gc1_att, const float* __restrict__ att1,
    const float* __restrict__ att2, const float* __restrict__ gc7_att,
    const float* __restrict__ g0, const float* __restrict__ be0, const float* __restrict__ b0,
    const float* __restrict__ g1a, const float* __restrict__ be1a, const float* __restrict__ b1a,
    const float* __restrict__ g2a, const float* __restrict__ be2a, const float* __restrict__ b2a,
    float* __restrict__ dct, short* __restrict__ w1T, short* __restrict__ w2T,
    short* __restrict__ wgT, short* __restrict__ gc1wT, short* __restrict__ aG,
    unsigned* __restrict__ bnP)
{
  __shared__ short tle[64][72];
  int bid = blockIdx.x, tid = threadIdx.x;
  if (bid < 2){
    int t = bid*256 + tid;
    if (t < 400){
      int k = t / 20, i = t % 20;
      double w = (k == 0) ? sqrt(1.0/20.0) : sqrt(2.0/20.0);
      dct[t] = (float)(w * cos(3.14159265358979323846 * (i + 0.5) * k / 20.0));
    }
  } else if (bid < 1026){
    int idx = (bid-2)*256 + tid;
    int f = idx >> 9, k = idx & 511;
    float v = 0.f;
    if (k < 396){
      int h = k / 66, c = k - h*66;
      const float* s = (f < 256) ? wK1 : wQ1;
      v = s[((f & 255)*66 + c)*6 + h];
    }
    w1T[idx] = f2bf(v);
  } else if (bid < 3586){
    int idx = (bid-1026)*256 + tid;
    int f = idx / 1280, k = idx - f*1280;
    int h = k >> 8, c = k & 255;
    const float* s = (f < 256) ? wK2 : wQ2;
    w2T[idx] = f2bf(s[((f & 255)*256 + c)*5 + h]);
  } else if (bid < 3970){
    int q = bid - 3586;
    int l = q >> 4, sub = q & 15;
    int kt = (sub >> 2)*64, ft = (sub & 3)*64;
    const float* s = (l < 12) ? (gw1 + l*65536) : (gw2 + (l-12)*65536);
    int c = tid & 63, r4 = tid >> 6;
    #pragma unroll
    for (int p = 0; p < 16; p++){
      int k = p*4 + r4;
      tle[k][c] = f2bf(s[(kt + k)*256 + ft + c]);
    }
    __syncthreads();
    #pragma unroll
    for (int p = 0; p < 16; p++){
      int f = p*4 + r4;
      wgT[l*65536 + (ft + f)*256 + kt + c] = tle[c][f];
    }
  } else if (bid < 4002){
    int idx = (bid-3970)*256 + tid;
    int f = idx >> 5, k = idx & 31;
    gc1wT[idx] = f2bf(k < 20 ? gc1_w[k*256 + f] : 0.f);
  } else if (bid < 4782){
    int idx = (bid-4002)*256 + tid;   // < 26*7680 = 199680 exactly
    int li = idx / 7680, r = idx - li*7680;
    int n = r / 96, m = r - n*96;
    const float* Af;
    if (li == 0) Af = gc1_att;
    else if (li == 25) Af = gc7_att;
    else if (li & 1) Af = att1 + ((li-1)>>1)*4356;
    else             Af = att2 + ((li-2)>>1)*4356;
    aG[idx] = f2bf((n < 66 && m < 66) ? Af[n*66 + m] : 0.f);
  } else {
    int idx = (bid-4782)*256 + tid;
    if (idx < 25*16896){
      int li = idx / 16896, r = idx - li*16896;
      int f = r & 255;
      const float *g, *be, *bi;
      if (li == 0){ g = g0; be = be0; bi = b0; }
      else {
        int l = (li - 1) >> 1;
        if (li & 1){ g = g1a + l*16896; be = be1a + l*16896; bi = b1a + l*256; }
        else       { g = g2a + l*16896; be = be2a + l*16896; bi = b2a + l*256; }
      }
      float sc = g[r] * BNI;
      float sh = bi[f] * sc + be[r];
      bnP[idx] = pk2(sc, sh);
    }
  }
}

// ---------------- conv1 (proven) ----------------
__global__ __launch_bounds__(256) void k_conv1(const float* __restrict__ src,
    const short* __restrict__ w1T, short* __restrict__ kc1q){
  int b = blockIdx.x, ns = blockIdx.y;
  int f0 = ns*128;
  __shared__ short Aim[48*424];
  __shared__ short Wt[128*72];
  int tid = threadIdx.x;
  for (int idx = tid; idx < 48*424; idx += 256){
    int t = idx / 424, kk = idx - t*424;
    float v = 0.f;
    if (kk < 396 && t < 40){
      int h = kk / 66, c = kk - h*66;
      int row = t + h + ((t >= 35) ? 5 : 0);
      v = src[(b*50 + row)*66 + c] * 1e-3f;
    }
    Aim[idx] = f2bf(v);
  }
  int w = tid >> 6, lane = tid & 63, fl = lane & 15, g = lane >> 4;
  float4v acc[3][2];
  #pragma unroll
  for (int i=0;i<3;i++) for (int n=0;n<2;n++) acc[i][n] = (float4v){0.f,0.f,0.f,0.f};
  for (int kt = 0; kt < 416; kt += 64){
    __syncthreads();
    for (int ch = tid; ch < 128*8; ch += 256){
      int r = ch >> 3, kq = ch & 7;
      *(short8*)&Wt[r*72 + kq*8] = *(const short8*)&w1T[(f0 + r)*512 + kt + kq*8];
    }
    __syncthreads();
    int nst = (416 - kt >= 64) ? 2 : 1;
    for (int s = 0; s < nst; s++){
      int k0 = s*32;
      short8 bfr0 = *(const short8*)&Wt[(w*32 + fl)*72 + k0 + g*8];
      short8 bfr1 = *(const short8*)&Wt[(w*32 + 16 + fl)*72 + k0 + g*8];
      #pragma unroll
      for (int i=0;i<3;i++){
        short8 afr = *(const short8*)&Aim[(i*16 + fl)*424 + kt + k0 + g*8];
        acc[i][0] = __builtin_amdgcn_mfma_f32_16x16x32_bf16(afr, bfr0, acc[i][0], 0,0,0);
        acc[i][1] = __builtin_amdgcn_mfma_f32_16x16x32_bf16(afr, bfr1, acc[i][1], 0,0,0);
      }
    }
  }
  #pragma unroll
  for (int i=0;i<3;i++) for (int n=0;n<2;n++) for (int j=0;j<4;j++){
    int t = i*16 + g*4 + j;
    int f = f0 + w*32 + n*16 + fl;
    float v = fmaxf(acc[i][n][j], 0.f);
    if (t < 35 && f < 256) kc1q[(b*40 + t)*256 + f] = f2bf(v);
    else if (t >= 35 && t < 40 && f >= 256) kc1q[(b*40 + t)*256 + (f - 256)] = f2bf(v);
  }
}

// ---------------- conv2 (proven) ----------------
__global__ __launch_bounds__(256) void k_conv2(const short* __restrict__ kc1q,
    const short* __restrict__ w2T, float* __restrict__ key, float* __restrict__ q){
  int b = blockIdx.x, ns = blockIdx.y;
  int f0 = ns*128;
  __shared__ short kcs[40*256];
  __shared__ short Wt[128*136];
  char* kcb = (char*)kcs;
  int tid = threadIdx.x;
  for (int ch = tid; ch < 1280; ch += 256){
    int r = ch >> 5, kq = ch & 31;
    unsigned byte = (unsigned)(r*512 + kq*16) ^ (unsigned)((r & 7) << 4);
    *(short8*)(kcb + byte) = *(const short8*)&kc1q[(b*40 + r)*256 + kq*8];
  }
  int w = tid >> 6, lane = tid & 63, fl = lane & 15, g = lane >> 4;
  float4v acc[2][2];
  #pragma unroll
  for (int i=0;i<2;i++) for (int n=0;n<2;n++) acc[i][n] = (float4v){0.f,0.f,0.f,0.f};
  for (int kt = 0; kt < 1280; kt += 128){
    __syncthreads();
    for (int ch = tid; ch < 128*16; ch += 256){
      int r = ch >> 4, kq = ch & 15;
      *(short8*)&Wt[r*136 + kq*8] = *(const short8*)&w2T[(f0 + r)*1280 + kt + kq*8];
    }
    __syncthreads();
    #pragma unroll
    for (int s = 0; s < 4; s++){
      int k = kt + s*32;
      int h = k >> 8, cb = k & 255;
      short8 bfr0 = *(const short8*)&Wt[(w*32 + fl)*136 + s*32 + g*8];
      short8 bfr1 = *(const short8*)&Wt[(w*32 + 16 + fl)*136 + s*32 + g*8];
      #pragma unroll
      for (int i=0;i<2;i++){
        int t = i*16 + fl;
        int row = t + h + ((t == 31) ? 4 : 0);
        unsigned byte = (unsigned)(row*512 + (cb + g*8)*2) ^ (unsigned)((row & 7) << 4);
        short8 afr = *(const short8*)(kcb + byte);
        acc[i][0] = __builtin_amdgcn_mfma_f32_16x16x32_bf16(afr, bfr0, acc[i][0], 0,0,0);
        acc[i][1] = __builtin_amdgcn_mfma_f32_16x16x32_bf16(afr, bfr1, acc[i][1], 0,0,0);
      }
    }
  }
  #pragma unroll
  for (int i=0;i<2;i++) for (int n=0;n<2;n++) for (int j=0;j<4;j++){
    int t = i*16 + g*4 + j;
    int f = f0 + w*32 + n*16 + fl;
    float v = fmaxf(acc[i][n][j], 0.f);
    if (t < 31 && f < 256) key[(b*31 + t)*256 + f] = v;
    else if (t == 31 && f >= 256) q[b*256 + f - 256] = v;
  }
}

// ---------------- fused attention + build_x (proven) ----------------
__global__ __launch_bounds__(256) void k_attx(const float* __restrict__ src,
    const float* __restrict__ q, const float* __restrict__ key,
    const float* __restrict__ dct, float* __restrict__ x, short* __restrict__ x_bf){
  int b = blockIdx.x;
  int tid = threadIdx.x;
  __shared__ float sred[31][9];
  __shared__ float a[31];
  __shared__ float z[20*66];
  for (int i = tid; i < 2560; i += 256) x_bf[b*2560 + i] = 0;
  if (tid < 248){
    int v = tid >> 3, p = tid & 7;
    const float* kr = key + (b*31 + v)*256 + p*32;
    const float* qr = q + b*256 + p*32;
    float s = 0.f;
    #pragma unroll
    for (int o = 0; o < 32; o++) s += qr[o] * kr[o];
    sred[v][p] = s;
  }
  __syncthreads();
  if (tid < 31){
    float s = 1e-15f;
    #pragma unroll
    for (int p = 0; p < 8; p++) s += sred[tid][p];
    sred[tid][8] = s;
  }
  __syncthreads();
  if (tid < 64){
    float v = (tid < 31) ? sred[tid][8] : 0.f;
    float tot = v;
    for (int off = 32; off; off >>= 1) tot += __shfl_down(tot, off);
    tot = __shfl(tot, 0);
    if (tid < 31) a[tid] = v / tot;
  }
  __syncthreads();
  for (int idx = tid; idx < 1320; idx += 256){
    int i = idx / 66, f = idx % 66;
    float s = 0.f;
    for (int v = 0; v < 31; v++) s += a[v] * src[(b*50 + v + i)*66 + f];
    z[idx] = s;
  }
  __syncthreads();
  for (int idx = tid; idx < 660; idx += 256){
    int f = idx / 10, k = idx % 10;
    float s1 = 0.f, s2 = 0.f;
    #pragma unroll
    for (int i = 0; i < 20; i++){
      float d = dct[k*20 + i];
      int tt = (i < 10) ? (40 + i) : 49;
      s1 += d * src[(b*50 + tt)*66 + f];
      s2 += d * z[i*66 + f];
    }
    x[(b*66 + f)*20 + k] = s1;
    x[(b*66 + f)*20 + 10 + k] = s2;
    x_bf[(b*80 + f)*32 + k] = f2bf(s1);
    x_bf[(b*80 + f)*32 + 10 + k] = f2bf(s2);
  }
}

// ---------------- mega kernel: single barrier per layer ----------------
// LDS (byte ^= ((row&15)<<4)):
//   ybf[2] [80 m][512 B] | tT [256 f][256 B] (wave-local rows)
// Wave w owns f-slice [32w, 32w+32).

// MODE: 0 = y_r = v (gc1), 1 = h (no residual), 2 = y_r += v
template<int KSTEPS, int KSTRIDE, int MODE>
__device__ __forceinline__ void layer_step(
    const short* __restrict__ Wg,
    const unsigned* __restrict__ bnl, const short* __restrict__ aGl,
    float4v (&y_r)[2][5], int w, int fl, int g,
    const char* __restrict__ yin, char* __restrict__ yout,
    char* __restrict__ tT_c)
{
  // W rotating prefetch (3 slots)
  const short* wbase = Wg + (w*32 + fl)*KSTRIDE + g*8;
  short8 bw[3][2];
  bw[0][0] = *(const short8*)(wbase);
  bw[0][1] = *(const short8*)(wbase + 16*KSTRIDE);
  if (KSTEPS > 1){
    bw[1][0] = *(const short8*)(wbase + 32);
    bw[1][1] = *(const short8*)(wbase + 16*KSTRIDE + 32);
  }

  // ---- G1: t = y @ W ----
  float4v acc[5][2];
  #pragma unroll
  for (int i=0;i<5;i++){ acc[i][0]=(float4v){0.f,0.f,0.f,0.f}; acc[i][1]=(float4v){0.f,0.f,0.f,0.f}; }
  __builtin_amdgcn_s_setprio(1);
  #pragma unroll
  for (int ks=0; ks<KSTEPS; ks++){
    if (ks + 2 < KSTEPS){
      bw[(ks+2)%3][0] = *(const short8*)(wbase + (ks+2)*32);
      bw[(ks+2)%3][1] = *(const short8*)(wbase + 16*KSTRIDE + (ks+2)*32);
    }
    #pragma unroll
    for (int i=0;i<5;i++){
      int m = i*16 + fl;
      short8 af = *(const short8*)(yin + m*512 + ((ks*64 + g*16) ^ ((m & 15) << 4)));
      acc[i][0] = __builtin_amdgcn_mfma_f32_16x16x32_bf16(af, bw[ks%3][0], acc[i][0], 0,0,0);
      acc[i][1] = __builtin_amdgcn_mfma_f32_16x16x32_bf16(af, bw[ks%3][1], acc[i][1], 0,0,0);
    }
  }
  __builtin_amdgcn_s_setprio(0);

  // A fragments for G2 step 0, issued while acc is packed (acc dying)
  short8 bA[5];
  #pragma unroll
  for (int n2=0;n2<5;n2++)
    bA[n2] = *(const short8*)&aGl[(n2*16 + fl)*96 + g*8];

  // pack acc -> tT (wave-local rows; in-wave lgkm ordering suffices)
  #pragma unroll
  for (int i=0;i<5;i++){
    int mb = (i*16 + g*4)*2;
    #pragma unroll
    for (int n=0;n<2;n++){
      int f = w*32 + n*16 + fl;
      uint2 u; u.x = pk2(acc[i][n][0], acc[i][n][1]); u.y = pk2(acc[i][n][2], acc[i][n][3]);
      *(uint2*)(tT_c + f*256 + (mb ^ ((f & 15) << 4))) = u;
    }
  }

  // ---- G2: o = A @ t (no barrier: tT wave-local, A from global) ----
  float4v a2[2][5];
  #pragma unroll
  for (int i=0;i<2;i++)
    #pragma unroll
    for (int n=0;n<5;n++) a2[i][n] = (float4v){0.f,0.f,0.f,0.f};
  uint4v bnp0[5];
  #pragma unroll
  for (int ks2=0; ks2<3; ks2++){
    __builtin_amdgcn_s_setprio(1);
    #pragma unroll
    for (int i2=0;i2<2;i2++){
      int f = w*32 + i2*16 + fl;
      short8 af = *(const short8*)(tT_c + f*256 + ((ks2*64 + g*16) ^ ((f & 15) << 4)));
      #pragma unroll
      for (int n2=0;n2<5;n2++)
        a2[i2][n2] = __builtin_amdgcn_mfma_f32_16x16x32_bf16(af, bA[n2], a2[i2][n2], 0,0,0);
    }
    __builtin_amdgcn_s_setprio(0);
    if (ks2 == 1){
      #pragma unroll
      for (int n2=0;n2<5;n2++){
        int n = n2*16 + fl; int ns = (n < 66) ? n : 0;
        bnp0[n2] = *(const uint4v*)&bnl[ns*256 + w*32 + g*4];
      }
    }
    if (ks2 < 2){
      #pragma unroll
      for (int n2=0;n2<5;n2++)
        bA[n2] = *(const short8*)&aGl[(n2*16 + fl)*96 + (ks2+1)*32 + g*8];
    }
  }

  // ---- epilogue: BN + tanh [+res] -> yout (double-buffered) ----
  uint4v bnp1[5];
  #pragma unroll
  for (int n2=0;n2<5;n2++){
    int n = n2*16 + fl; int ns = (n < 66) ? n : 0;
    bnp1[n2] = *(const uint4v*)&bnl[ns*256 + w*32 + 16 + g*4];
  }
  #pragma unroll
  for (int i2=0;i2<2;i2++){
    #pragma unroll
    for (int n2=0;n2<5;n2++){
      int n = n2*16 + fl;
      bool nok = (n < 66);
      float vv[4];
      #pragma unroll
      for (int j=0;j<4;j++){
        unsigned u = (i2 == 0) ? bnp0[n2][j] : bnp1[n2][j];
        float sc = __uint_as_float((u & 0xffffu) << 16);
        float sh = __uint_as_float(u & 0xffff0000u);
        float v = a2[i2][n2][j]*sc + sh;
        v = tanh_f(v);
        if (MODE == 0) y_r[i2][n2][j] = v;
        if (MODE == 2){ v += y_r[i2][n2][j]; y_r[i2][n2][j] = v; }
        vv[j] = nok ? v : 0.f;
      }
      int fb2 = (w*32 + i2*16 + g*4)*2;
      uint2 u2; u2.x = pk2(vv[0], vv[1]); u2.y = pk2(vv[2], vv[3]);
      *(uint2*)(yout + n*512 + (fb2 ^ ((n & 15) << 4))) = u2;
    }
  }
  __syncthreads();   // THE barrier: yout published for next layer
}

__global__ __launch_bounds__(512) void k_mega(const short* __restrict__ x_bf,
    const short* __restrict__ gc1wT, const short* __restrict__ wgT,
    const short* __restrict__ aG, const unsigned* __restrict__ bnP,
    const float* __restrict__ gc7_w, const float* __restrict__ gc7_b,
    const float* __restrict__ x, const float* __restrict__ dct,
    float* __restrict__ out)
{
  __shared__ __align__(16) char ybf_c[81920];   // [2][80][512 B]
  __shared__ __align__(16) char tT_c[65536];
  __shared__ float xo_l[1320];
  __shared__ float dct_l[400];

  int b = blockIdx.x, tid = threadIdx.x;
  int w = tid >> 6, lane = tid & 63, fl = lane & 15, g = lane >> 4;
  char* ybf0 = ybf_c;
  char* ybf1 = ybf_c + 40960;

  for (int i = tid; i < 4096; i += 512) ((float4v*)tT_c)[i] = (float4v){0.f,0.f,0.f,0.f};
  for (int i = tid; i < 400; i += 512) dct_l[i] = dct[i];
  for (int i = tid; i < 320; i += 512){
    int m = i >> 2, kq = i & 3;
    short8 v = *(const short8*)&x_bf[(b*80 + m)*32 + kq*8];
    *(short8*)(ybf0 + m*512 + ((kq*16) ^ ((m & 15) << 4))) = v;
  }
  __syncthreads();

  float4v y_r[2][5];

  // s=0: gc1 ybf0->ybf1; block l: L1 ybf1->ybf0, L2 ybf0->ybf1. Final: ybf1.
  layer_step<1,32,0>(gc1wT, bnP, aG, y_r, w, fl, g, ybf0, ybf1, tT_c);
  #pragma unroll 1
  for (int l = 0; l < 12; l++){
    layer_step<8,256,1>(wgT + l*65536, bnP + (1+2*l)*16896, aG + (1+2*l)*7680,
                        y_r, w, fl, g, ybf1, ybf0, tT_c);
    layer_step<8,256,2>(wgT + (12+l)*65536, bnP + (2+2*l)*16896, aG + (2+2*l)*7680,
                        y_r, w, fl, g, ybf0, ybf1, tT_c);
  }

  // ---- gc7 tail: stage w7 [32 f][256 k] bf16 into free ybf0 ----
  for (int i = tid; i < 2048; i += 512){
    int f = i >> 6, kq = (i & 63)*4;
    float v0=0.f, v1=0.f, v2=0.f, v3=0.f;
    if (f < 20){
      v0 = gc7_w[(kq+0)*20 + f]; v1 = gc7_w[(kq+1)*20 + f];
      v2 = gc7_w[(kq+2)*20 + f]; v3 = gc7_w[(kq+3)*20 + f];
    }
    uint2 u; u.x = pk2(v0, v1); u.y = pk2(v2, v3);
    *(uint2*)(ybf0 + f*512 + ((kq*2) ^ ((f & 15) << 4))) = u;
  }
  __syncthreads();

  // G1t: t2 = y @ w7 (N=32, K=256), all waves redundant, w0 writes tT
  float4v at[5][2];
  #pragma unroll
  for (int i=0;i<5;i++){ at[i][0] = (float4v){0.f,0.f,0.f,0.f}; at[i][1] = (float4v){0.f,0.f,0.f,0.f}; }
  #pragma unroll
  for (int ks = 0; ks < 8; ks++){
    short8 bf[2];
    #pragma unroll
    for (int n=0;n<2;n++){
      int f = n*16 + fl;
      bf[n] = *(const short8*)(ybf0 + f*512 + ((ks*64 + g*16) ^ ((f & 15) << 4)));
    }
    #pragma unroll
    for (int i=0;i<5;i++){
      int m = i*16 + fl;
      short8 af = *(const short8*)(ybf1 + m*512 + ((ks*64 + g*16) ^ ((m & 15) << 4)));
      at[i][0] = __builtin_amdgcn_mfma_f32_16x16x32_bf16(af, bf[0], at[i][0], 0,0,0);
      at[i][1] = __builtin_amdgcn_mfma_f32_16x16x32_bf16(af, bf[1], at[i][1], 0,0,0);
    }
  }
  if (w == 0){
    #pragma unroll
    for (int i=0;i<5;i++){
      int mb = (i*16 + g*4)*2;
      #pragma unroll
      for (int n=0;n<2;n++){
        int f = n*16 + fl;
        uint2 u; u.x = pk2(at[i][n][0], at[i][n][1]); u.y = pk2(at[i][n][2], at[i][n][3]);
        *(uint2*)(tT_c + f*256 + (mb ^ ((f & 15) << 4))) = u;
      }
    }
  }
  // A7 fragments from global (y_r dead in tail -> 60 regs fine)
  short8 bAt[15];
  {
    const short* aGt = aG + 25*7680;
    #pragma unroll
    for (int ks=0;ks<3;ks++)
      #pragma unroll
      for (int n2=0;n2<5;n2++)
        bAt[ks*5+n2] = *(const short8*)&aGt[(n2*16 + fl)*96 + ks*32 + g*8];
  }
  __syncthreads();

  // G2't: out'[f][n] = t2_T @ A7^T, all waves redundant, w0 epilogue
  float4v a2t[2][5];
  #pragma unroll
  for (int i=0;i<2;i++)
    #pragma unroll
    for (int n=0;n<5;n++) a2t[i][n] = (float4v){0.f,0.f,0.f,0.f};
  #pragma unroll
  for (int ks = 0; ks < 3; ks++){
    #pragma unroll
    for (int i2=0;i2<2;i2++){
      int f = i2*16 + fl;
      short8 af = *(const short8*)(tT_c + f*256 + ((ks*64 + g*16) ^ ((f & 15) << 4)));
      #pragma unroll
      for (int n2=0;n2<5;n2++)
        a2t[i2][n2] = __builtin_amdgcn_mfma_f32_16x16x32_bf16(af, bAt[ks*5+n2], a2t[i2][n2], 0,0,0);
    }
  }
  if (w == 0){
    #pragma unroll
    for (int i2=0;i2<2;i2++){
      #pragma unroll
      for (int n2=0;n2<5;n2++){
        int n = n2*16 + fl;
        #pragma unroll
        for (int j=0;j<4;j++){
          int f = i2*16 + g*4 + j;
          if (f < 20 && n < 66)
            xo_l[n*20 + f] = a2t[i2][n2][j] + gc7_b[f] + x[(b*66 + n)*20 + f];
        }
      }
    }
  }
  __syncthreads();

  for (int idx = tid; idx < 1320; idx += 512){
    int r = idx / 66, fn = idx % 66;
    float s = 0.f;
    #pragma unroll
    for (int k = 0; k < 10; k++) s += dct_l[k*20 + r] * xo_l[fn*20 + k];
    out[(b*20 + r)*66 + fn] = s;
  }
}

extern "C" void kernel_launch(void* const* d_in, const int* in_sizes, int n_in,
                              void* d_out, int out_size, void* d_ws, size_t ws_size,
                              hipStream_t stream) {
  const float* src      = (const float*)d_in[0];
  const float* convQ_w1 = (const float*)d_in[1];
  const float* convQ_w2 = (const float*)d_in[2];
  const float* convK_w1 = (const float*)d_in[3];
  const float* convK_w2 = (const float*)d_in[4];
  const float* gc1_w    = (const float*)d_in[5];
  const float* gc1_att  = (const float*)d_in[6];
  const float* gc1_b    = (const float*)d_in[7];
  const float* bn1_g    = (const float*)d_in[8];
  const float* bn1_b    = (const float*)d_in[9];
  const float* gcb_w1   = (const float*)d_in[10];
  const float* gcb_att1 = (const float*)d_in[11];
  const float* gcb_b1   = (const float*)d_in[12];
  const float* gcb_bn1g = (const float*)d_in[13];
  const float* gcb_bn1b = (const float*)d_in[14];
  const float* gcb_w2   = (const float*)d_in[15];
  const float* gcb_att2 = (const float*)d_in[16];
  const float* gcb_b2   = (const float*)d_in[17];
  const float* gcb_bn2g = (const float*)d_in[18];
  const float* gcb_bn2b = (const float*)d_in[19];
  const float* gc7_w    = (const float*)d_in[20];
  const float* gc7_att  = (const float*)d_in[21];
  const float* gc7_b    = (const float*)d_in[22];
  float* out = (float*)d_out;

  float* ws    = (float*)d_ws;
  float* dct   = ws;
  float* x     = ws + 512;
  short* x_bf  = (short*)(ws + 169472);
  short* wgT   = (short*)(ws + 333312);
  short* gc1wT = (short*)(ws + 1119744);
  short* w1T   = (short*)(ws + 1123840);
  short* w2T   = (short*)(ws + 1254912);
  short* kc1q  = (short*)(ws + 1582592);
  float* key   = ws + 2237952;
  float* q     = ws + 3253760;
  unsigned* bnP= (unsigned*)(ws + 3290624);
  short* aG    = (short*)(ws + 3713024);

  k_prep<<<6432, 256, 0, stream>>>(convK_w1, convQ_w1, convK_w2, convQ_w2,
      gcb_w1, gcb_w2, gc1_w,
      gc1_att, gcb_att1, gcb_att2, gc7_att,
      bn1_g, bn1_b, gc1_b, gcb_bn1g, gcb_bn1b, gcb_b1,
      gcb_bn2g, gcb_bn2b, gcb_b2,
      dct, w1T, w2T, wgT, gc1wT, aG, bnP);

  k_conv1<<<dim3(128,4), 256, 0, stream>>>(src, w1T, kc1q);
  k_conv2<<<dim3(128,4), 256, 0, stream>>>(kc1q, w2T, key, q);
  k_attx<<<128, 256, 0, stream>>>(src, q, key, dct, x, x_bf);

  k_mega<<<128, 512, 0, stream>>>(x_bf, gc1wT, wgT, aG, bnP,
      gc7_w, gc7_b, x, dct, out);
}

// Round 17
// 276.994 us; speedup vs baseline: 3.2456x; 1.0416x over previous
//
#include <hip/hip_runtime.h>
#include <hip/hip_bf16.h>

// HisRepItself round 17: r13/r16 mega + attx folded into mega prologue.
//  - k_attx deleted: each mega block computes its batch's attention +
//    build_x in-prologue (tT_c as f32 scratch, zeroed after -- the old
//    prologue zeroed it anyway). x kept in LDS x_l for the tail (removes
//    tail's global x read); bf16 x written straight into swizzled ybf0.
//  - Saves 1 launch + x/x_bf global round trip. Layer loop byte-identical
//    to r13 (best proven: mega 218us, no spill).
//
// Workspace (f32 units): dct 0 | wgT 333312 | gc1wT 1119744 | w1T 1123840
//   w2T 1254912 | kc1q 1582592 | key 2237952 | q 3253760 | bnP 3290624
//   aG 3713024 (26*7680 shorts)   (x/x_bf slots unused now)

typedef __attribute__((ext_vector_type(8))) short short8;
typedef __attribute__((ext_vector_type(4))) float float4v;
typedef __attribute__((ext_vector_type(4))) unsigned uint4v;

#define BNI 0.9999950000374995f

__device__ __forceinline__ short f2bf(float x){
  unsigned u = __float_as_uint(x);
  unsigned r = (u + 0x7fff + ((u >> 16) & 1)) >> 16;
  return (short)r;
}
__device__ __forceinline__ unsigned pk2(float a, float b){
  unsigned r;
  asm("v_cvt_pk_bf16_f32 %0, %1, %2" : "=v"(r) : "v"(a), "v"(b));
  return r;
}
__device__ __forceinline__ float tanh_f(float x){
  x = fminf(fmaxf(x, -9.f), 9.f);
  float e = __expf(2.f * x);
  return (e - 1.f) * __builtin_amdgcn_rcpf(e + 1.f);
}

// ---------------- merged prep kernel (proven) ----------------
// grid: [0,2) dct | [2,1026) wconv1 | [1026,3586) wconv2 | [3586,3970) wgcn
//       [3970,4002) wgc1 | [4002,4782) aG | [4782,6432) bnpack
__global__ __launch_bounds__(256) void k_prep(
    const float* __restrict__ wK1, const float* __restrict__ wQ1,
    const float* __restrict__ wK2, const float* __restrict__ wQ2,
    const float* __restrict__ gw1, const float* __restrict__ gw2,
    const float* __restrict__ gc1_w,
    const float* __restrict__ gc1_att, const float* __restrict__ att1,
    const float* __restrict__ att2, const float* __restrict__ gc7_att,
    const float* __restrict__ g0, const float* __restrict__ be0, const float* __restrict__ b0,
    const float* __restrict__ g1a, const float* __restrict__ be1a, const float* __restrict__ b1a,
    const float* __restrict__ g2a, const float* __restrict__ be2a, const float* __restrict__ b2a,
    float* __restrict__ dct, short* __restrict__ w1T, short* __restrict__ w2T,
    short* __restrict__ wgT, short* __restrict__ gc1wT, short* __restrict__ aG,
    unsigned* __restrict__ bnP)
{
  __shared__ short tle[64][72];
  int bid = blockIdx.x, tid = threadIdx.x;
  if (bid < 2){
    int t = bid*256 + tid;
    if (t < 400){
      int k = t / 20, i = t % 20;
      double w = (k == 0) ? sqrt(1.0/20.0) : sqrt(2.0/20.0);
      dct[t] = (float)(w * cos(3.14159265358979323846 * (i + 0.5) * k / 20.0));
    }
  } else if (bid < 1026){
    int idx = (bid-2)*256 + tid;
    int f = idx >> 9, k = idx & 511;
    float v = 0.f;
    if (k < 396){
      int h = k / 66, c = k - h*66;
      const float* s = (f < 256) ? wK1 : wQ1;
      v = s[((f & 255)*66 + c)*6 + h];
    }
    w1T[idx] = f2bf(v);
  } else if (bid < 3586){
    int idx = (bid-1026)*256 + tid;
    int f = idx / 1280, k = idx - f*1280;
    int h = k >> 8, c = k & 255;
    const float* s = (f < 256) ? wK2 : wQ2;
    w2T[idx] = f2bf(s[((f & 255)*256 + c)*5 + h]);
  } else if (bid < 3970){
    int q = bid - 3586;
    int l = q >> 4, sub = q & 15;
    int kt = (sub >> 2)*64, ft = (sub & 3)*64;
    const float* s = (l < 12) ? (gw1 + l*65536) : (gw2 + (l-12)*65536);
    int c = tid & 63, r4 = tid >> 6;
    #pragma unroll
    for (int p = 0; p < 16; p++){
      int k = p*4 + r4;
      tle[k][c] = f2bf(s[(kt + k)*256 + ft + c]);
    }
    __syncthreads();
    #pragma unroll
    for (int p = 0; p < 16; p++){
      int f = p*4 + r4;
      wgT[l*65536 + (ft + f)*256 + kt + c] = tle[c][f];
    }
  } else if (bid < 4002){
    int idx = (bid-3970)*256 + tid;
    int f = idx >> 5, k = idx & 31;
    gc1wT[idx] = f2bf(k < 20 ? gc1_w[k*256 + f] : 0.f);
  } else if (bid < 4782){
    int idx = (bid-4002)*256 + tid;   // < 26*7680 = 199680 exactly
    int li = idx / 7680, r = idx - li*7680;
    int n = r / 96, m = r - n*96;
    const float* Af;
    if (li == 0) Af = gc1_att;
    else if (li == 25) Af = gc7_att;
    else if (li & 1) Af = att1 + ((li-1)>>1)*4356;
    else             Af = att2 + ((li-2)>>1)*4356;
    aG[idx] = f2bf((n < 66 && m < 66) ? Af[n*66 + m] : 0.f);
  } else {
    int idx = (bid-4782)*256 + tid;
    if (idx < 25*16896){
      int li = idx / 16896, r = idx - li*16896;
      int f = r & 255;
      const float *g, *be, *bi;
      if (li == 0){ g = g0; be = be0; bi = b0; }
      else {
        int l = (li - 1) >> 1;
        if (li & 1){ g = g1a + l*16896; be = be1a + l*16896; bi = b1a + l*256; }
        else       { g = g2a + l*16896; be = be2a + l*16896; bi = b2a + l*256; }
      }
      float sc = g[r] * BNI;
      float sh = bi[f] * sc + be[r];
      bnP[idx] = pk2(sc, sh);
    }
  }
}

// ---------------- conv1 (proven) ----------------
__global__ __launch_bounds__(256) void k_conv1(const float* __restrict__ src,
    const short* __restrict__ w1T, short* __restrict__ kc1q){
  int b = blockIdx.x, ns = blockIdx.y;
  int f0 = ns*128;
  __shared__ short Aim[48*424];
  __shared__ short Wt[128*72];
  int tid = threadIdx.x;
  for (int idx = tid; idx < 48*424; idx += 256){
    int t = idx / 424, kk = idx - t*424;
    float v = 0.f;
    if (kk < 396 && t < 40){
      int h = kk / 66, c = kk - h*66;
      int row = t + h + ((t >= 35) ? 5 : 0);
      v = src[(b*50 + row)*66 + c] * 1e-3f;
    }
    Aim[idx] = f2bf(v);
  }
  int w = tid >> 6, lane = tid & 63, fl = lane & 15, g = lane >> 4;
  float4v acc[3][2];
  #pragma unroll
  for (int i=0;i<3;i++) for (int n=0;n<2;n++) acc[i][n] = (float4v){0.f,0.f,0.f,0.f};
  for (int kt = 0; kt < 416; kt += 64){
    __syncthreads();
    for (int ch = tid; ch < 128*8; ch += 256){
      int r = ch >> 3, kq = ch & 7;
      *(short8*)&Wt[r*72 + kq*8] = *(const short8*)&w1T[(f0 + r)*512 + kt + kq*8];
    }
    __syncthreads();
    int nst = (416 - kt >= 64) ? 2 : 1;
    for (int s = 0; s < nst; s++){
      int k0 = s*32;
      short8 bfr0 = *(const short8*)&Wt[(w*32 + fl)*72 + k0 + g*8];
      short8 bfr1 = *(const short8*)&Wt[(w*32 + 16 + fl)*72 + k0 + g*8];
      #pragma unroll
      for (int i=0;i<3;i++){
        short8 afr = *(const short8*)&Aim[(i*16 + fl)*424 + kt + k0 + g*8];
        acc[i][0] = __builtin_amdgcn_mfma_f32_16x16x32_bf16(afr, bfr0, acc[i][0], 0,0,0);
        acc[i][1] = __builtin_amdgcn_mfma_f32_16x16x32_bf16(afr, bfr1, acc[i][1], 0,0,0);
      }
    }
  }
  #pragma unroll
  for (int i=0;i<3;i++) for (int n=0;n<2;n++) for (int j=0;j<4;j++){
    int t = i*16 + g*4 + j;
    int f = f0 + w*32 + n*16 + fl;
    float v = fmaxf(acc[i][n][j], 0.f);
    if (t < 35 && f < 256) kc1q[(b*40 + t)*256 + f] = f2bf(v);
    else if (t >= 35 && t < 40 && f >= 256) kc1q[(b*40 + t)*256 + (f - 256)] = f2bf(v);
  }
}

// ---------------- conv2 (proven) ----------------
__global__ __launch_bounds__(256) void k_conv2(const short* __restrict__ kc1q,
    const short* __restrict__ w2T, float* __restrict__ key, float* __restrict__ q){
  int b = blockIdx.x, ns = blockIdx.y;
  int f0 = ns*128;
  __shared__ short kcs[40*256];
  __shared__ short Wt[128*136];
  char* kcb = (char*)kcs;
  int tid = threadIdx.x;
  for (int ch = tid; ch < 1280; ch += 256){
    int r = ch >> 5, kq = ch & 31;
    unsigned byte = (unsigned)(r*512 + kq*16) ^ (unsigned)((r & 7) << 4);
    *(short8*)(kcb + byte) = *(const short8*)&kc1q[(b*40 + r)*256 + kq*8];
  }
  int w = tid >> 6, lane = tid & 63, fl = lane & 15, g = lane >> 4;
  float4v acc[2][2];
  #pragma unroll
  for (int i=0;i<2;i++) for (int n=0;n<2;n++) acc[i][n] = (float4v){0.f,0.f,0.f,0.f};
  for (int kt = 0; kt < 1280; kt += 128){
    __syncthreads();
    for (int ch = tid; ch < 128*16; ch += 256){
      int r = ch >> 4, kq = ch & 15;
      *(short8*)&Wt[r*136 + kq*8] = *(const short8*)&w2T[(f0 + r)*1280 + kt + kq*8];
    }
    __syncthreads();
    #pragma unroll
    for (int s = 0; s < 4; s++){
      int k = kt + s*32;
      int h = k >> 8, cb = k & 255;
      short8 bfr0 = *(const short8*)&Wt[(w*32 + fl)*136 + s*32 + g*8];
      short8 bfr1 = *(const short8*)&Wt[(w*32 + 16 + fl)*136 + s*32 + g*8];
      #pragma unroll
      for (int i=0;i<2;i++){
        int t = i*16 + fl;
        int row = t + h + ((t == 31) ? 4 : 0);
        unsigned byte = (unsigned)(row*512 + (cb + g*8)*2) ^ (unsigned)((row & 7) << 4);
        short8 afr = *(const short8*)(kcb + byte);
        acc[i][0] = __builtin_amdgcn_mfma_f32_16x16x32_bf16(afr, bfr0, acc[i][0], 0,0,0);
        acc[i][1] = __builtin_amdgcn_mfma_f32_16x16x32_bf16(afr, bfr1, acc[i][1], 0,0,0);
      }
    }
  }
  #pragma unroll
  for (int i=0;i<2;i++) for (int n=0;n<2;n++) for (int j=0;j<4;j++){
    int t = i*16 + g*4 + j;
    int f = f0 + w*32 + n*16 + fl;
    float v = fmaxf(acc[i][n][j], 0.f);
    if (t < 31 && f < 256) key[(b*31 + t)*256 + f] = v;
    else if (t == 31 && f >= 256) q[b*256 + f - 256] = v;
  }
}

// ---------------- mega kernel: attx prologue + single-barrier layers ----
// LDS (byte ^= ((row&15)<<4)):
//   ybf[2] [80 m][512 B] | tT [256 f][256 B] (wave-local rows; also f32
//   scratch for the attention prologue) | x_l [66*20] f32 for the tail.
// Wave w owns f-slice [32w, 32w+32).

// MODE: 0 = y_r = v (gc1), 1 = h (no residual), 2 = y_r += v
template<int KSTEPS, int KSTRIDE, int MODE>
__device__ __forceinline__ void layer_step(
    const short* __restrict__ Wg,
    const unsigned* __restrict__ bnl, const short* __restrict__ aGl,
    float4v (&y_r)[2][5], int w, int fl, int g,
    const char* __restrict__ yin, char* __restrict__ yout,
    char* __restrict__ tT_c)
{
  // W rotating prefetch (3 slots)
  const short* wbase = Wg + (w*32 + fl)*KSTRIDE + g*8;
  short8 bw[3][2];
  bw[0][0] = *(const short8*)(wbase);
  bw[0][1] = *(const short8*)(wbase + 16*KSTRIDE);
  if (KSTEPS > 1){
    bw[1][0] = *(const short8*)(wbase + 32);
    bw[1][1] = *(const short8*)(wbase + 16*KSTRIDE + 32);
  }

  // ---- G1: t = y @ W ----
  float4v acc[5][2];
  #pragma unroll
  for (int i=0;i<5;i++){ acc[i][0]=(float4v){0.f,0.f,0.f,0.f}; acc[i][1]=(float4v){0.f,0.f,0.f,0.f}; }
  __builtin_amdgcn_s_setprio(1);
  #pragma unroll
  for (int ks=0; ks<KSTEPS; ks++){
    if (ks + 2 < KSTEPS){
      bw[(ks+2)%3][0] = *(const short8*)(wbase + (ks+2)*32);
      bw[(ks+2)%3][1] = *(const short8*)(wbase + 16*KSTRIDE + (ks+2)*32);
    }
    #pragma unroll
    for (int i=0;i<5;i++){
      int m = i*16 + fl;
      short8 af = *(const short8*)(yin + m*512 + ((ks*64 + g*16) ^ ((m & 15) << 4)));
      acc[i][0] = __builtin_amdgcn_mfma_f32_16x16x32_bf16(af, bw[ks%3][0], acc[i][0], 0,0,0);
      acc[i][1] = __builtin_amdgcn_mfma_f32_16x16x32_bf16(af, bw[ks%3][1], acc[i][1], 0,0,0);
    }
  }
  __builtin_amdgcn_s_setprio(0);

  // A fragments for G2 step 0, issued while acc is packed (acc dying)
  short8 bA[5];
  #pragma unroll
  for (int n2=0;n2<5;n2++)
    bA[n2] = *(const short8*)&aGl[(n2*16 + fl)*96 + g*8];

  // pack acc -> tT (wave-local rows; in-wave lgkm ordering suffices)
  #pragma unroll
  for (int i=0;i<5;i++){
    int mb = (i*16 + g*4)*2;
    #pragma unroll
    for (int n=0;n<2;n++){
      int f = w*32 + n*16 + fl;
      uint2 u; u.x = pk2(acc[i][n][0], acc[i][n][1]); u.y = pk2(acc[i][n][2], acc[i][n][3]);
      *(uint2*)(tT_c + f*256 + (mb ^ ((f & 15) << 4))) = u;
    }
  }

  // ---- G2: o = A @ t (no barrier: tT wave-local, A from global) ----
  float4v a2[2][5];
  #pragma unroll
  for (int i=0;i<2;i++)
    #pragma unroll
    for (int n=0;n<5;n++) a2[i][n] = (float4v){0.f,0.f,0.f,0.f};
  uint4v bnp0[5];
  #pragma unroll
  for (int ks2=0; ks2<3; ks2++){
    __builtin_amdgcn_s_setprio(1);
    #pragma unroll
    for (int i2=0;i2<2;i2++){
      int f = w*32 + i2*16 + fl;
      short8 af = *(const short8*)(tT_c + f*256 + ((ks2*64 + g*16) ^ ((f & 15) << 4)));
      #pragma unroll
      for (int n2=0;n2<5;n2++)
        a2[i2][n2] = __builtin_amdgcn_mfma_f32_16x16x32_bf16(af, bA[n2], a2[i2][n2], 0,0,0);
    }
    __builtin_amdgcn_s_setprio(0);
    if (ks2 == 1){
      #pragma unroll
      for (int n2=0;n2<5;n2++){
        int n = n2*16 + fl; int ns = (n < 66) ? n : 0;
        bnp0[n2] = *(const uint4v*)&bnl[ns*256 + w*32 + g*4];
      }
    }
    if (ks2 < 2){
      #pragma unroll
      for (int n2=0;n2<5;n2++)
        bA[n2] = *(const short8*)&aGl[(n2*16 + fl)*96 + (ks2+1)*32 + g*8];
    }
  }

  // ---- epilogue: BN + tanh [+res] -> yout (double-buffered) ----
  uint4v bnp1[5];
  #pragma unroll
  for (int n2=0;n2<5;n2++){
    int n = n2*16 + fl; int ns = (n < 66) ? n : 0;
    bnp1[n2] = *(const uint4v*)&bnl[ns*256 + w*32 + 16 + g*4];
  }
  #pragma unroll
  for (int i2=0;i2<2;i2++){
    #pragma unroll
    for (int n2=0;n2<5;n2++){
      int n = n2*16 + fl;
      bool nok = (n < 66);
      float vv[4];
      #pragma unroll
      for (int j=0;j<4;j++){
        unsigned u = (i2 == 0) ? bnp0[n2][j] : bnp1[n2][j];
        float sc = __uint_as_float((u & 0xffffu) << 16);
        float sh = __uint_as_float(u & 0xffff0000u);
        float v = a2[i2][n2][j]*sc + sh;
        v = tanh_f(v);
        if (MODE == 0) y_r[i2][n2][j] = v;
        if (MODE == 2){ v += y_r[i2][n2][j]; y_r[i2][n2][j] = v; }
        vv[j] = nok ? v : 0.f;
      }
      int fb2 = (w*32 + i2*16 + g*4)*2;
      uint2 u2; u2.x = pk2(vv[0], vv[1]); u2.y = pk2(vv[2], vv[3]);
      *(uint2*)(yout + n*512 + (fb2 ^ ((n & 15) << 4))) = u2;
    }
  }
  __syncthreads();   // THE barrier: yout published for next layer
}

__global__ __launch_bounds__(512) void k_mega(const float* __restrict__ src,
    const float* __restrict__ keyv, const float* __restrict__ qv,
    const short* __restrict__ gc1wT, const short* __restrict__ wgT,
    const short* __restrict__ aG, const unsigned* __restrict__ bnP,
    const float* __restrict__ gc7_w, const float* __restrict__ gc7_b,
    const float* __restrict__ dct, float* __restrict__ out)
{
  __shared__ __align__(16) char ybf_c[81920];   // [2][80][512 B]
  __shared__ __align__(16) char tT_c[65536];
  __shared__ float xo_l[1320];
  __shared__ float x_l[1320];
  __shared__ float dct_l[400];

  int b = blockIdx.x, tid = threadIdx.x;
  int w = tid >> 6, lane = tid & 63, fl = lane & 15, g = lane >> 4;
  char* ybf0 = ybf_c;
  char* ybf1 = ybf_c + 40960;

  // ================= attx prologue (was k_attx) =================
  float* scr = (float*)tT_c;   // sred[31][17] @0, a @528, z @560..1880

  for (int i = tid; i < 10240; i += 512) ((int*)ybf0)[i] = 0;   // zero ybf0
  for (int i = tid; i < 400; i += 512) dct_l[i] = dct[i];
  if (tid < 496){
    int v = tid >> 4, p = tid & 15;
    const float* kr = keyv + (b*31 + v)*256 + p*16;
    const float* qr = qv + b*256 + p*16;
    float s = 0.f;
    #pragma unroll
    for (int o = 0; o < 16; o++) s += qr[o] * kr[o];
    scr[v*17 + p] = s;
  }
  __syncthreads();
  if (tid < 31){
    float s = 1e-15f;
    #pragma unroll
    for (int p = 0; p < 16; p++) s += scr[tid*17 + p];
    scr[528 + tid] = s;
  }
  __syncthreads();
  if (tid < 64){
    float v = (tid < 31) ? scr[528 + tid] : 0.f;
    float tot = v;
    for (int off = 32; off; off >>= 1) tot += __shfl_down(tot, off);
    tot = __shfl(tot, 0);
    if (tid < 31) scr[528 + tid] = v / tot;
  }
  __syncthreads();
  for (int idx = tid; idx < 1320; idx += 512){
    int i = idx / 66, f = idx - (idx/66)*66;
    float s = 0.f;
    for (int v = 0; v < 31; v++) s += scr[528 + v] * src[(b*50 + v + i)*66 + f];
    scr[560 + idx] = s;
  }
  __syncthreads();
  for (int idx = tid; idx < 660; idx += 512){
    int f = idx / 10, k = idx - (idx/10)*10;
    float s1 = 0.f, s2 = 0.f;
    #pragma unroll
    for (int i = 0; i < 20; i++){
      float d = dct_l[k*20 + i];
      int tt = (i < 10) ? (40 + i) : 49;
      s1 += d * src[(b*50 + tt)*66 + f];
      s2 += d * scr[560 + i*66 + f];
    }
    x_l[f*20 + k] = s1;
    x_l[f*20 + 10 + k] = s2;
    *(short*)(ybf0 + f*512 + ((2*k) ^ ((f & 15) << 4))) = f2bf(s1);
    *(short*)(ybf0 + f*512 + ((2*(10 + k)) ^ ((f & 15) << 4))) = f2bf(s2);
  }
  __syncthreads();
  // clear tT (scratch done; also provides zero pad for m in [80,96))
  for (int i = tid; i < 4096; i += 512) ((float4v*)tT_c)[i] = (float4v){0.f,0.f,0.f,0.f};
  __syncthreads();
  // ================= end prologue =================

  float4v y_r[2][5];

  // s=0: gc1 ybf0->ybf1; block l: L1 ybf1->ybf0, L2 ybf0->ybf1. Final: ybf1.
  layer_step<1,32,0>(gc1wT, bnP, aG, y_r, w, fl, g, ybf0, ybf1, tT_c);
  #pragma unroll 1
  for (int l = 0; l < 12; l++){
    layer_step<8,256,1>(wgT + l*65536, bnP + (1+2*l)*16896, aG + (1+2*l)*7680,
                        y_r, w, fl, g, ybf1, ybf0, tT_c);
    layer_step<8,256,2>(wgT + (12+l)*65536, bnP + (2+2*l)*16896, aG + (2+2*l)*7680,
                        y_r, w, fl, g, ybf0, ybf1, tT_c);
  }

  // ---- gc7 tail: stage w7 [32 f][256 k] bf16 into free ybf0 ----
  for (int i = tid; i < 2048; i += 512){
    int f = i >> 6, kq = (i & 63)*4;
    float v0=0.f, v1=0.f, v2=0.f, v3=0.f;
    if (f < 20){
      v0 = gc7_w[(kq+0)*20 + f]; v1 = gc7_w[(kq+1)*20 + f];
      v2 = gc7_w[(kq+2)*20 + f]; v3 = gc7_w[(kq+3)*20 + f];
    }
    uint2 u; u.x = pk2(v0, v1); u.y = pk2(v2, v3);
    *(uint2*)(ybf0 + f*512 + ((kq*2) ^ ((f & 15) << 4))) = u;
  }
  __syncthreads();

  // G1t: t2 = y @ w7 (N=32, K=256), all waves redundant, w0 writes tT
  float4v at[5][2];
  #pragma unroll
  for (int i=0;i<5;i++){ at[i][0] = (float4v){0.f,0.f,0.f,0.f}; at[i][1] = (float4v){0.f,0.f,0.f,0.f}; }
  #pragma unroll
  for (int ks = 0; ks < 8; ks++){
    short8 bf[2];
    #pragma unroll
    for (int n=0;n<2;n++){
      int f = n*16 + fl;
      bf[n] = *(const short8*)(ybf0 + f*512 + ((ks*64 + g*16) ^ ((f & 15) << 4)));
    }
    #pragma unroll
    for (int i=0;i<5;i++){
      int m = i*16 + fl;
      short8 af = *(const short8*)(ybf1 + m*512 + ((ks*64 + g*16) ^ ((m & 15) << 4)));
      at[i][0] = __builtin_amdgcn_mfma_f32_16x16x32_bf16(af, bf[0], at[i][0], 0,0,0);
      at[i][1] = __builtin_amdgcn_mfma_f32_16x16x32_bf16(af, bf[1], at[i][1], 0,0,0);
    }
  }
  if (w == 0){
    #pragma unroll
    for (int i=0;i<5;i++){
      int mb = (i*16 + g*4)*2;
      #pragma unroll
      for (int n=0;n<2;n++){
        int f = n*16 + fl;
        uint2 u; u.x = pk2(at[i][n][0], at[i][n][1]); u.y = pk2(at[i][n][2], at[i][n][3]);
        *(uint2*)(tT_c + f*256 + (mb ^ ((f & 15) << 4))) = u;
      }
    }
  }
  // A7 fragments from global (y_r dead in tail)
  short8 bAt[15];
  {
    const short* aGt = aG + 25*7680;
    #pragma unroll
    for (int ks=0;ks<3;ks++)
      #pragma unroll
      for (int n2=0;n2<5;n2++)
        bAt[ks*5+n2] = *(const short8*)&aGt[(n2*16 + fl)*96 + ks*32 + g*8];
  }
  __syncthreads();

  // G2't: out'[f][n] = t2_T @ A7^T, all waves redundant, w0 epilogue
  float4v a2t[2][5];
  #pragma unroll
  for (int i=0;i<2;i++)
    #pragma unroll
    for (int n=0;n<5;n++) a2t[i][n] = (float4v){0.f,0.f,0.f,0.f};
  #pragma unroll
  for (int ks = 0; ks < 3; ks++){
    #pragma unroll
    for (int i2=0;i2<2;i2++){
      int f = i2*16 + fl;
      short8 af = *(const short8*)(tT_c + f*256 + ((ks*64 + g*16) ^ ((f & 15) << 4)));
      #pragma unroll
      for (int n2=0;n2<5;n2++)
        a2t[i2][n2] = __builtin_amdgcn_mfma_f32_16x16x32_bf16(af, bAt[ks*5+n2], a2t[i2][n2], 0,0,0);
    }
  }
  if (w == 0){
    #pragma unroll
    for (int i2=0;i2<2;i2++){
      #pragma unroll
      for (int n2=0;n2<5;n2++){
        int n = n2*16 + fl;
        #pragma unroll
        for (int j=0;j<4;j++){
          int f = i2*16 + g*4 + j;
          if (f < 20 && n < 66)
            xo_l[n*20 + f] = a2t[i2][n2][j] + gc7_b[f] + x_l[n*20 + f];
        }
      }
    }
  }
  __syncthreads();

  for (int idx = tid; idx < 1320; idx += 512){
    int r = idx / 66, fn = idx % 66;
    float s = 0.f;
    #pragma unroll
    for (int k = 0; k < 10; k++) s += dct_l[k*20 + r] * xo_l[fn*20 + k];
    out[(b*20 + r)*66 + fn] = s;
  }
}

extern "C" void kernel_launch(void* const* d_in, const int* in_sizes, int n_in,
                              void* d_out, int out_size, void* d_ws, size_t ws_size,
                              hipStream_t stream) {
  const float* src      = (const float*)d_in[0];
  const float* convQ_w1 = (const float*)d_in[1];
  const float* convQ_w2 = (const float*)d_in[2];
  const float* convK_w1 = (const float*)d_in[3];
  const float* convK_w2 = (const float*)d_in[4];
  const float* gc1_w    = (const float*)d_in[5];
  const float* gc1_att  = (const float*)d_in[6];
  const float* gc1_b    = (const float*)d_in[7];
  const float* bn1_g    = (const float*)d_in[8];
  const float* bn1_b    = (const float*)d_in[9];
  const float* gcb_w1   = (const float*)d_in[10];
  const float* gcb_att1 = (const float*)d_in[11];
  const float* gcb_b1   = (const float*)d_in[12];
  const float* gcb_bn1g = (const float*)d_in[13];
  const float* gcb_bn1b = (const float*)d_in[14];
  const float* gcb_w2   = (const float*)d_in[15];
  const float* gcb_att2 = (const float*)d_in[16];
  const float* gcb_b2   = (const float*)d_in[17];
  const float* gcb_bn2g = (const float*)d_in[18];
  const float* gcb_bn2b = (const float*)d_in[19];
  const float* gc7_w    = (const float*)d_in[20];
  const float* gc7_att  = (const float*)d_in[21];
  const float* gc7_b    = (const float*)d_in[22];
  float* out = (float*)d_out;

  float* ws    = (float*)d_ws;
  float* dct   = ws;
  short* wgT   = (short*)(ws + 333312);
  short* gc1wT = (short*)(ws + 1119744);
  short* w1T   = (short*)(ws + 1123840);
  short* w2T   = (short*)(ws + 1254912);
  short* kc1q  = (short*)(ws + 1582592);
  float* key   = ws + 2237952;
  float* q     = ws + 3253760;
  unsigned* bnP= (unsigned*)(ws + 3290624);
  short* aG    = (short*)(ws + 3713024);

  k_prep<<<6432, 256, 0, stream>>>(convK_w1, convQ_w1, convK_w2, convQ_w2,
      gcb_w1, gcb_w2, gc1_w,
      gc1_att, gcb_att1, gcb_att2, gc7_att,
      bn1_g, bn1_b, gc1_b, gcb_bn1g, gcb_bn1b, gcb_b1,
      gcb_bn2g, gcb_bn2b, gcb_b2,
      dct, w1T, w2T, wgT, gc1wT, aG, bnP);

  k_conv1<<<dim3(128,4), 256, 0, stream>>>(src, w1T, kc1q);
  k_conv2<<<dim3(128,4), 256, 0, stream>>>(kc1q, w2T, key, q);

  k_mega<<<128, 512, 0, stream>>>(src, key, q, gc1wT, wgT, aG, bnP,
      gc7_w, gc7_b, dct, out);
}